// Round 3
// baseline (2098.291 us; speedup 1.0000x reference)
//
#include <hip/hip_runtime.h>
#include <cmath>

namespace {
constexpr int BPTS  = 16384;
constexpr int NPOSE = 32;
constexpr int KV    = 8;
constexpr int HD    = 256;
constexpr int TM    = 64;
constexpr int FROW  = 44;     // feat row stride (pad 39->44, 16B-aligned)

constexpr size_t OFF_XLOCAL = 0;
constexpr size_t OFF_XLA    = (size_t)BPTS * 3;                      // x_local_all [32,16384,3]
constexpr size_t OFF_MINENC = OFF_XLA + (size_t)NPOSE * BPTS * 3;    // min_encodings [16384,32]
constexpr size_t OFF_POSEQ  = OFF_MINENC + (size_t)BPTS * NPOSE;     // inv_pose_q [16384,4,4]
constexpr size_t OFF_CLASS  = OFF_POSEQ + (size_t)BPTS * 16;         // pred_class [16384,1]
constexpr size_t OFF_PRED   = OFF_CLASS + (size_t)BPTS;              // pred_prob.T [16384,32]
constexpr size_t OFF_VECQ   = OFF_PRED + (size_t)BPTS * NPOSE;       // vec_q [16384,8]
}

// 512 threads: tr = tid>>5 (16 row-groups of 4 rows), tc = tid&31 (col groups).
// acc[i][j]: row tr*4+i, cols j<4 -> tc*4+j ; j>=4 -> 128+tc*4+(j-4).
// A-reads: float4 along k, same address across the 32-lane tc group -> LDS broadcast.
// Stores/weight-loads: half-wave contiguous 512B -> conflict-free / coalesced.
template<int KDIM, int RS>
__device__ __forceinline__ void gemm_layer(const float* __restrict__ W,
                                           const float* __restrict__ B,
                                           const float (*in)[RS],
                                           float acc[4][8], int tc, int tr)
{
    {
        float4 bA = *(const float4*)(B + tc*4);
        float4 bB = *(const float4*)(B + 128 + tc*4);
        #pragma unroll
        for (int i = 0; i < 4; ++i) {
            acc[i][0]=bA.x; acc[i][1]=bA.y; acc[i][2]=bA.z; acc[i][3]=bA.w;
            acc[i][4]=bB.x; acc[i][5]=bB.y; acc[i][6]=bB.z; acc[i][7]=bB.w;
        }
    }
    constexpr int K4 = KDIM & ~3;
    #pragma unroll 2
    for (int k = 0; k < K4; k += 4) {
        float4 a4[4];
        #pragma unroll
        for (int i = 0; i < 4; ++i) a4[i] = *(const float4*)&in[tr*4+i][k];
        #pragma unroll
        for (int kk = 0; kk < 4; ++kk) {
            float4 wA = *(const float4*)(W + (size_t)(k+kk)*HD + tc*4);
            float4 wB = *(const float4*)(W + (size_t)(k+kk)*HD + 128 + tc*4);
            #pragma unroll
            for (int i = 0; i < 4; ++i) {
                const float a = (kk==0) ? a4[i].x : (kk==1) ? a4[i].y
                              : (kk==2) ? a4[i].z : a4[i].w;
                acc[i][0] = fmaf(a, wA.x, acc[i][0]);
                acc[i][1] = fmaf(a, wA.y, acc[i][1]);
                acc[i][2] = fmaf(a, wA.z, acc[i][2]);
                acc[i][3] = fmaf(a, wA.w, acc[i][3]);
                acc[i][4] = fmaf(a, wB.x, acc[i][4]);
                acc[i][5] = fmaf(a, wB.y, acc[i][5]);
                acc[i][6] = fmaf(a, wB.z, acc[i][6]);
                acc[i][7] = fmaf(a, wB.w, acc[i][7]);
            }
        }
    }
    if constexpr (K4 < KDIM) {
        #pragma unroll
        for (int k = K4; k < KDIM; ++k) {
            float4 wA = *(const float4*)(W + (size_t)k*HD + tc*4);
            float4 wB = *(const float4*)(W + (size_t)k*HD + 128 + tc*4);
            #pragma unroll
            for (int i = 0; i < 4; ++i) {
                const float a = in[tr*4+i][k];
                acc[i][0] = fmaf(a, wA.x, acc[i][0]);
                acc[i][1] = fmaf(a, wA.y, acc[i][1]);
                acc[i][2] = fmaf(a, wA.z, acc[i][2]);
                acc[i][3] = fmaf(a, wA.w, acc[i][3]);
                acc[i][4] = fmaf(a, wB.x, acc[i][4]);
                acc[i][5] = fmaf(a, wB.y, acc[i][5]);
                acc[i][6] = fmaf(a, wB.z, acc[i][6]);
                acc[i][7] = fmaf(a, wB.w, acc[i][7]);
            }
        }
    }
}

// 512 threads, 2 blocks/CU (LDS 77KB) -> 16 waves/CU = 4 waves/SIMD (50% occ)
__global__ __launch_bounds__(512, 4)
void mlp_kernel(const float* __restrict__ x_world,
                const float* __restrict__ inv_poses,
                const float* __restrict__ w0, const float* __restrict__ b0,
                const float* __restrict__ w1, const float* __restrict__ b1,
                const float* __restrict__ w2, const float* __restrict__ b2,
                const float* __restrict__ w3, const float* __restrict__ b3,
                float* __restrict__ out)
{
    __shared__ float feat[TM][FROW];   // embedded features, row-major
    __shared__ float h[TM][HD];        // activations, row-major (reused in place)
    __shared__ float predp[TM];

    const int tid = threadIdx.x;
    const int bid = blockIdx.x;
    const int n_idx = bid >> 8;          // 256 blocks per pose (16384/64)
    const int bbase = (bid & 255) * TM;

    // ---- pose transform + positional encoding (8 wave-replicas share 64 points) ----
    {
        const int r = tid & 63;
        const int q = tid >> 6;          // 0..7
        const int b = bbase + r;
        const float xw0 = x_world[b*3+0];
        const float xw1 = x_world[b*3+1];
        const float xw2 = x_world[b*3+2];
        const float* P = inv_poses + n_idx*16;
        float xl[3];
        #pragma unroll
        for (int x = 0; x < 3; ++x)
            xl[x] = P[x*4+3] + P[x*4+0]*xw0 + P[x*4+1]*xw1 + P[x*4+2]*xw2;
        if (q == 0) {
            float* xla = out + OFF_XLA + ((size_t)n_idx*BPTS + b)*3;
            #pragma unroll
            for (int x = 0; x < 3; ++x) { xla[x] = xl[x]; feat[r][x] = xl[x]; }
        }
        // 12 jobs (6 octaves x sin/cos): q handles job q, and q<4 also job q+8
        #pragma unroll
        for (int t = 0; t < 2; ++t) {
            const int jj = q + 8*t;
            if (jj < 12) {
                const int oct = jj >> 1;
                const int fn  = jj & 1;
                const float s = (float)(1 << oct);
                #pragma unroll
                for (int x = 0; x < 3; ++x) {
                    float a = xl[x] * s;
                    feat[r][3 + 6*oct + 3*fn + x] = fn ? cosf(a) : sinf(a);
                }
            }
        }
    }
    __syncthreads();

    const int tc = tid & 31;   // col group
    const int tr = tid >> 5;   // row group: rows tr*4 .. tr*4+3
    float acc[4][8];

    // ---- layer 0: feat(39) -> h0 ----
    gemm_layer<39, FROW>(w0, b0, feat, acc, tc, tr);
    #pragma unroll
    for (int i = 0; i < 4; ++i) {       // relu -> h (feat distinct, no pre-barrier)
        float4 v0 = make_float4(fmaxf(acc[i][0],0.f), fmaxf(acc[i][1],0.f),
                                fmaxf(acc[i][2],0.f), fmaxf(acc[i][3],0.f));
        float4 v1 = make_float4(fmaxf(acc[i][4],0.f), fmaxf(acc[i][5],0.f),
                                fmaxf(acc[i][6],0.f), fmaxf(acc[i][7],0.f));
        *(float4*)&h[tr*4+i][tc*4]       = v0;
        *(float4*)&h[tr*4+i][128 + tc*4] = v1;
    }
    __syncthreads();

    // ---- layer 1 (in-place: read all of h, barrier, overwrite) ----
    gemm_layer<HD, HD>(w1, b1, h, acc, tc, tr);
    __syncthreads();
    #pragma unroll
    for (int i = 0; i < 4; ++i) {
        float4 v0 = make_float4(fmaxf(acc[i][0],0.f), fmaxf(acc[i][1],0.f),
                                fmaxf(acc[i][2],0.f), fmaxf(acc[i][3],0.f));
        float4 v1 = make_float4(fmaxf(acc[i][4],0.f), fmaxf(acc[i][5],0.f),
                                fmaxf(acc[i][6],0.f), fmaxf(acc[i][7],0.f));
        *(float4*)&h[tr*4+i][tc*4]       = v0;
        *(float4*)&h[tr*4+i][128 + tc*4] = v1;
    }
    __syncthreads();

    // ---- layer 2 ----
    gemm_layer<HD, HD>(w2, b2, h, acc, tc, tr);

    // ---- layer 3 from registers: pred[row] = sum_c relu(h2[row][c]) * w3[c] ----
    {
        float4 wA = *(const float4*)(w3 + tc*4);
        float4 wB = *(const float4*)(w3 + 128 + tc*4);
        float v[4];
        #pragma unroll
        for (int i = 0; i < 4; ++i) {
            float s;
            s = fmaxf(acc[i][0],0.f) * wA.x;
            s = fmaf(fmaxf(acc[i][1],0.f), wA.y, s);
            s = fmaf(fmaxf(acc[i][2],0.f), wA.z, s);
            s = fmaf(fmaxf(acc[i][3],0.f), wA.w, s);
            s = fmaf(fmaxf(acc[i][4],0.f), wB.x, s);
            s = fmaf(fmaxf(acc[i][5],0.f), wB.y, s);
            s = fmaf(fmaxf(acc[i][6],0.f), wB.z, s);
            s = fmaf(fmaxf(acc[i][7],0.f), wB.w, s);
            v[i] = s;
        }
        #pragma unroll
        for (int m = 16; m >= 1; m >>= 1) {    // reduce across the 32-lane tc group
            #pragma unroll
            for (int i = 0; i < 4; ++i) v[i] += __shfl_xor(v[i], m);
        }
        if (tc == 0) {
            #pragma unroll
            for (int i = 0; i < 4; ++i) predp[tr*4+i] = v[i];
        }
    }
    __syncthreads();
    if (tid < TM) {
        float p = predp[tid] + b3[0];
        out[OFF_PRED + (size_t)(bbase + tid)*NPOSE + n_idx] = p;
    }
}

__global__ __launch_bounds__(256)
void select_kernel(const float* __restrict__ x_world,
                   const float* __restrict__ inv_poses,
                   const float* __restrict__ vector,
                   float* __restrict__ out)
{
    const int b = blockIdx.x * 256 + threadIdx.x;
    if (b >= BPTS) return;

    const float* pr = out + OFF_PRED + (size_t)b * NPOSE;
    float best = pr[0];
    int idx = 0;
    #pragma unroll
    for (int n = 1; n < NPOSE; ++n) {           // first-occurrence min == jnp.argmin
        float v = pr[n];
        if (v < best) { best = v; idx = n; }
    }

    float* me = out + OFF_MINENC + (size_t)b * NPOSE;
    #pragma unroll
    for (int n = 0; n < NPOSE; ++n) me[n] = (n == idx) ? 1.f : 0.f;

    const float* P = inv_poses + idx * 16;
    float* pq = out + OFF_POSEQ + (size_t)b * 16;
    #pragma unroll
    for (int m = 0; m < 16; ++m) pq[m] = P[m];

    const float xw0 = x_world[b*3+0], xw1 = x_world[b*3+1], xw2 = x_world[b*3+2];
    float* xl = out + OFF_XLOCAL + (size_t)b * 3;
    #pragma unroll
    for (int x = 0; x < 3; ++x)
        xl[x] = P[x*4+3] + P[x*4+0]*xw0 + P[x*4+1]*xw1 + P[x*4+2]*xw2;

    out[OFF_CLASS + b] = (float)idx;

    const float* vq = vector + idx * KV;
    float* ov = out + OFF_VECQ + (size_t)b * KV;
    #pragma unroll
    for (int m = 0; m < KV; ++m) ov[m] = vq[m];
}

extern "C" void kernel_launch(void* const* d_in, const int* in_sizes, int n_in,
                              void* d_out, int out_size, void* d_ws, size_t ws_size,
                              hipStream_t stream)
{
    const float* x_world   = (const float*)d_in[0];
    const float* inv_poses = (const float*)d_in[1];
    const float* vector    = (const float*)d_in[2];
    const float* w0 = (const float*)d_in[3];
    const float* b0 = (const float*)d_in[4];
    const float* w1 = (const float*)d_in[5];
    const float* b1 = (const float*)d_in[6];
    const float* w2 = (const float*)d_in[7];
    const float* b2 = (const float*)d_in[8];
    const float* w3 = (const float*)d_in[9];
    const float* b3 = (const float*)d_in[10];
    float* out = (float*)d_out;

    mlp_kernel<<<dim3(NPOSE * BPTS / TM), dim3(512), 0, stream>>>(
        x_world, inv_poses, w0, b0, w1, b1, w2, b2, w3, b3, out);
    select_kernel<<<dim3(BPTS / 256), dim3(256), 0, stream>>>(
        x_world, inv_poses, vector, out);
}

// Round 4
// 496.617 us; speedup vs baseline: 4.2252x; 4.2252x over previous
//
#include <hip/hip_runtime.h>
#include <cmath>

namespace {
constexpr int BPTS  = 16384;
constexpr int NPOSE = 32;
constexpr int KV    = 8;
constexpr int HD    = 256;
constexpr int TM    = 128;      // points per block

constexpr size_t OFF_XLOCAL = 0;
constexpr size_t OFF_XLA    = (size_t)BPTS * 3;
constexpr size_t OFF_MINENC = OFF_XLA + (size_t)NPOSE * BPTS * 3;
constexpr size_t OFF_POSEQ  = OFF_MINENC + (size_t)BPTS * NPOSE;
constexpr size_t OFF_CLASS  = OFF_POSEQ + (size_t)BPTS * 16;
constexpr size_t OFF_PRED   = OFF_CLASS + (size_t)BPTS;
constexpr size_t OFF_VECQ   = OFF_PRED + (size_t)BPTS * NPOSE;

// workspace (f16 elements): weight fragment buffers, hi/lo split
constexpr size_t WS_W0H = 0;         // 16 nt * 2 kc * 64 lanes * 8 e
constexpr size_t WS_W0L = 16384;
constexpr size_t WS_W1H = 32768;     // 16 nt * 8 kc * 512
constexpr size_t WS_W1L = 98304;
constexpr size_t WS_W2H = 163840;
constexpr size_t WS_W2L = 229376;
}

typedef _Float16 f16;
typedef __attribute__((ext_vector_type(8))) _Float16 f16x8;
typedef __attribute__((ext_vector_type(4))) float    f32x4;

#define MFMA16(a, b, c) __builtin_amdgcn_mfma_f32_16x16x32_f16((a), (b), (c), 0, 0, 0)

// ---- LDS activation planes: h[row][col] f16, XOR-swizzled to kill the
// stride-512B same-bank pattern on b128 A-fragment reads (guide §6 G4).
__device__ __forceinline__ f16x8 lds_readA(const f16* base, int row, int k) {
    int byte = row * 512 + k * 2;
    byte ^= (row & 7) << 4;
    return *(const f16x8*)((const char*)base + byte);
}
__device__ __forceinline__ void lds_writeH(f16* base, int row, int col, f16 v) {
    int byte = row * 512 + col * 2;
    byte ^= (row & 7) << 4;
    *(f16*)((char*)base + byte) = v;
}

// ---- weight prep: split fp32 W[k][col] into hi/lo f16 MFMA fragments.
// Fragment layout: idx = ((nt*KC + kc)*64 + lane)*8 + e, holding
// W[k = kc*32 + (lane>>4)*8 + e][col = nt*16 + (lane&15)].
// Same (g,e)->k convention is used for A-frags, so any hw k-permutation cancels.
__global__ __launch_bounds__(256)
void prep_w0(const float* __restrict__ w, f16* __restrict__ dh, f16* __restrict__ dl)
{
    int i = blockIdx.x * 256 + threadIdx.x;      // 16384 total
    int e  = i & 7;
    int l  = (i >> 3) & 63;
    int kc = (i >> 9) & 1;
    int nt = i >> 10;
    int k   = kc * 32 + ((l >> 4) << 3) + e;
    int col = nt * 16 + (l & 15);
    float v = (k < 39) ? w[k * HD + col] : 0.f;
    f16 hi = (f16)v;
    dh[i] = hi;
    dl[i] = (f16)(v - (float)hi);
}

__global__ __launch_bounds__(256)
void prep_whd(const float* __restrict__ w, f16* __restrict__ dh, f16* __restrict__ dl)
{
    int i = blockIdx.x * 256 + threadIdx.x;      // 65536 total
    int e  = i & 7;
    int l  = (i >> 3) & 63;
    int kc = (i >> 9) & 7;
    int nt = i >> 12;
    int k   = kc * 32 + ((l >> 4) << 3) + e;
    int col = nt * 16 + (l & 15);
    float v = w[k * HD + col];
    f16 hi = (f16)v;
    dh[i] = hi;
    dl[i] = (f16)(v - (float)hi);
}

// one 256-col x K=256 layer: acc[mt][nt] over 2 mtiles x 8 ntiles per wave
__device__ __forceinline__ void hd_layer(const f16* __restrict__ wfh,
                                         const f16* __restrict__ wfl,
                                         const float* __restrict__ bias,
                                         const f16* h_hi, const f16* h_lo,
                                         f32x4 acc[2][8], int mt0, int nb, int lane)
{
    const int l15 = lane & 15;
    const int g   = lane >> 4;
    #pragma unroll
    for (int nt = 0; nt < 8; ++nt) {
        float cb = bias[nb * 128 + nt * 16 + l15];
        f32x4 t = {cb, cb, cb, cb};
        acc[0][nt] = t; acc[1][nt] = t;
    }
    #pragma unroll
    for (int kc = 0; kc < 8; ++kc) {
        f16x8 ah[2], al[2];
        #pragma unroll
        for (int mt = 0; mt < 2; ++mt) {
            int row = (mt0 + mt) * 16 + l15;
            int k   = kc * 32 + g * 8;
            ah[mt] = lds_readA(h_hi, row, k);
            al[mt] = lds_readA(h_lo, row, k);
        }
        #pragma unroll
        for (int nt = 0; nt < 8; ++nt) {
            int off = (((nb * 8 + nt) * 8 + kc) * 64 + lane) * 8;
            f16x8 bh = *(const f16x8*)(wfh + off);
            f16x8 bl = *(const f16x8*)(wfl + off);
            #pragma unroll
            for (int mt = 0; mt < 2; ++mt) {
                acc[mt][nt] = MFMA16(ah[mt], bh, acc[mt][nt]);
                acc[mt][nt] = MFMA16(al[mt], bh, acc[mt][nt]);
                acc[mt][nt] = MFMA16(ah[mt], bl, acc[mt][nt]);
            }
        }
    }
}

__global__ __launch_bounds__(512, 2)
void mlp_kernel(const float* __restrict__ x_world,
                const float* __restrict__ inv_poses,
                const float* __restrict__ b0, const float* __restrict__ b1,
                const float* __restrict__ b2, const float* __restrict__ w3,
                const float* __restrict__ b3, const f16* __restrict__ wf,
                float* __restrict__ out)
{
    __shared__ f16 h_hi[TM * HD];       // 64 KB
    __shared__ f16 h_lo[TM * HD];       // 64 KB
    __shared__ f16 feat_hi[TM * 40];    // 10 KB (stride 80B: conflict-benign)
    __shared__ f16 feat_lo[TM * 40];
    __shared__ float predp[TM * 2];

    const int tid  = threadIdx.x;
    const int lane = tid & 63;
    const int wid  = tid >> 6;          // 8 waves
    const int l15  = lane & 15;
    const int g    = lane >> 4;
    const int mt0  = (wid & 3) * 2;     // wave owns mtiles mt0, mt0+1 (32 rows)
    const int nb   = wid >> 2;          // col half: ntiles nb*8 .. nb*8+7

    const int bid   = blockIdx.x;
    const int n_idx = bid >> 7;         // 128 blocks per pose
    const int bbase = (bid & 127) * TM;

    const f16* w0f_hi = wf + WS_W0H;
    const f16* w0f_lo = wf + WS_W0L;
    const f16* w1f_hi = wf + WS_W1H;
    const f16* w1f_lo = wf + WS_W1L;
    const f16* w2f_hi = wf + WS_W2H;
    const f16* w2f_lo = wf + WS_W2L;

    // ---- pose transform + positional encoding (wave covers mtile mt0+nb) ----
    {
        const int me = mt0 + nb;
        const int r  = me * 16 + l15;
        const int b  = bbase + r;
        const float xw0 = x_world[b*3+0], xw1 = x_world[b*3+1], xw2 = x_world[b*3+2];
        const float* P = inv_poses + n_idx * 16;
        float xl[3];
        #pragma unroll
        for (int x = 0; x < 3; ++x)
            xl[x] = P[x*4+3] + P[x*4+0]*xw0 + P[x*4+1]*xw1 + P[x*4+2]*xw2;

        auto put = [&](int c, float v) {
            f16 hi = (f16)v;
            feat_hi[r*40 + c] = hi;
            feat_lo[r*40 + c] = (f16)(v - (float)hi);
        };
        auto oct = [&](int o) {
            const float s = (float)(1 << o);
            #pragma unroll
            for (int x = 0; x < 3; ++x) {
                float a = xl[x] * s;
                put(3 + 6*o + x,     sinf(a));
                put(3 + 6*o + 3 + x, cosf(a));
            }
        };
        if (g == 0) {
            float* xla = out + OFF_XLA + ((size_t)n_idx * BPTS + b) * 3;
            #pragma unroll
            for (int x = 0; x < 3; ++x) { xla[x] = xl[x]; put(x, xl[x]); }
            put(39, 0.f);                 // k-pad
            oct(0);
        } else if (g == 1) { oct(1); oct(2); }
        else if (g == 2)   { oct(3); oct(4); }
        else               { oct(5); }
    }
    __syncthreads();

    f32x4 acc[2][8];

    // ---- layer 0: feat(39, padded 40/64) -> h0 ----
    #pragma unroll
    for (int nt = 0; nt < 8; ++nt) {
        float cb = b0[nb * 128 + nt * 16 + l15];
        f32x4 t = {cb, cb, cb, cb};
        acc[0][nt] = t; acc[1][nt] = t;
    }
    #pragma unroll
    for (int kc = 0; kc < 2; ++kc) {
        f16x8 ah[2], al[2];
        const f16x8 fz = {};
        #pragma unroll
        for (int mt = 0; mt < 2; ++mt) {
            int row = (mt0 + mt) * 16 + l15;
            int ke  = (kc == 0) ? g * 8 : (g == 0 ? 32 : 0);   // clamp: stay in-bounds
            ah[mt] = *(const f16x8*)&feat_hi[row * 40 + ke];
            al[mt] = *(const f16x8*)&feat_lo[row * 40 + ke];
            if (kc == 1 && g != 0) { ah[mt] = fz; al[mt] = fz; }  // only g==0 holds k=32..39
        }
        #pragma unroll
        for (int nt = 0; nt < 8; ++nt) {
            int off = (((nb * 8 + nt) * 2 + kc) * 64 + lane) * 8;
            f16x8 bh = *(const f16x8*)(w0f_hi + off);
            f16x8 bl = *(const f16x8*)(w0f_lo + off);
            #pragma unroll
            for (int mt = 0; mt < 2; ++mt) {
                acc[mt][nt] = MFMA16(ah[mt], bh, acc[mt][nt]);
                acc[mt][nt] = MFMA16(al[mt], bh, acc[mt][nt]);
                acc[mt][nt] = MFMA16(ah[mt], bl, acc[mt][nt]);
            }
        }
    }
    // relu + split -> h (first write, only barrier after)
    #pragma unroll
    for (int mt = 0; mt < 2; ++mt)
        #pragma unroll
        for (int nt = 0; nt < 8; ++nt)
            #pragma unroll
            for (int reg = 0; reg < 4; ++reg) {
                int row = (mt0 + mt) * 16 + g * 4 + reg;     // D: col=l&15, row=(l>>4)*4+reg
                int col = nb * 128 + nt * 16 + l15;
                float v = fmaxf(acc[mt][nt][reg], 0.f);
                f16 hi = (f16)v;
                lds_writeH(h_hi, row, col, hi);
                lds_writeH(h_lo, row, col, (f16)(v - (float)hi));
            }
    __syncthreads();

    // ---- layer 1 (in-place h: reads all cols of own rows incl. partner's) ----
    hd_layer(w1f_hi, w1f_lo, b1, h_hi, h_lo, acc, mt0, nb, lane);
    __syncthreads();                     // pair-wave reads of h0 complete
    #pragma unroll
    for (int mt = 0; mt < 2; ++mt)
        #pragma unroll
        for (int nt = 0; nt < 8; ++nt)
            #pragma unroll
            for (int reg = 0; reg < 4; ++reg) {
                int row = (mt0 + mt) * 16 + g * 4 + reg;
                int col = nb * 128 + nt * 16 + l15;
                float v = fmaxf(acc[mt][nt][reg], 0.f);
                f16 hi = (f16)v;
                lds_writeH(h_hi, row, col, hi);
                lds_writeH(h_lo, row, col, (f16)(v - (float)hi));
            }
    __syncthreads();

    // ---- layer 2 (no store; layer 3 straight from registers) ----
    hd_layer(w2f_hi, w2f_lo, b2, h_hi, h_lo, acc, mt0, nb, lane);

    // ---- layer 3: pred[row] = sum_col relu(h2)*w3 ----
    {
        float p[2][4] = {};
        #pragma unroll
        for (int nt = 0; nt < 8; ++nt) {
            float wv = w3[nb * 128 + nt * 16 + l15];
            #pragma unroll
            for (int mt = 0; mt < 2; ++mt)
                #pragma unroll
                for (int reg = 0; reg < 4; ++reg)
                    p[mt][reg] = fmaf(fmaxf(acc[mt][nt][reg], 0.f), wv, p[mt][reg]);
        }
        #pragma unroll
        for (int m = 8; m >= 1; m >>= 1)
            #pragma unroll
            for (int mt = 0; mt < 2; ++mt)
                #pragma unroll
                for (int reg = 0; reg < 4; ++reg)
                    p[mt][reg] += __shfl_xor(p[mt][reg], m);
        if (l15 == 0) {
            #pragma unroll
            for (int mt = 0; mt < 2; ++mt)
                #pragma unroll
                for (int reg = 0; reg < 4; ++reg) {
                    int row = (mt0 + mt) * 16 + g * 4 + reg;
                    predp[row * 2 + nb] = p[mt][reg];
                }
        }
    }
    __syncthreads();
    if (tid < TM) {
        float v = predp[tid * 2] + predp[tid * 2 + 1] + b3[0];
        out[OFF_PRED + (size_t)(bbase + tid) * NPOSE + n_idx] = v;
    }
}

__global__ __launch_bounds__(256)
void select_kernel(const float* __restrict__ x_world,
                   const float* __restrict__ inv_poses,
                   const float* __restrict__ vector,
                   float* __restrict__ out)
{
    const int b = blockIdx.x * 256 + threadIdx.x;
    if (b >= BPTS) return;

    const float* pr = out + OFF_PRED + (size_t)b * NPOSE;
    float best = pr[0];
    int idx = 0;
    #pragma unroll
    for (int n = 1; n < NPOSE; ++n) {           // first-occurrence min == jnp.argmin
        float v = pr[n];
        if (v < best) { best = v; idx = n; }
    }

    float* me = out + OFF_MINENC + (size_t)b * NPOSE;
    #pragma unroll
    for (int n = 0; n < NPOSE; ++n) me[n] = (n == idx) ? 1.f : 0.f;

    const float* P = inv_poses + idx * 16;
    float* pq = out + OFF_POSEQ + (size_t)b * 16;
    #pragma unroll
    for (int m = 0; m < 16; ++m) pq[m] = P[m];

    const float xw0 = x_world[b*3+0], xw1 = x_world[b*3+1], xw2 = x_world[b*3+2];
    float* xl = out + OFF_XLOCAL + (size_t)b * 3;
    #pragma unroll
    for (int x = 0; x < 3; ++x)
        xl[x] = P[x*4+3] + P[x*4+0]*xw0 + P[x*4+1]*xw1 + P[x*4+2]*xw2;

    out[OFF_CLASS + b] = (float)idx;

    const float* vq = vector + idx * KV;
    float* ov = out + OFF_VECQ + (size_t)b * KV;
    #pragma unroll
    for (int m = 0; m < KV; ++m) ov[m] = vq[m];
}

extern "C" void kernel_launch(void* const* d_in, const int* in_sizes, int n_in,
                              void* d_out, int out_size, void* d_ws, size_t ws_size,
                              hipStream_t stream)
{
    const float* x_world   = (const float*)d_in[0];
    const float* inv_poses = (const float*)d_in[1];
    const float* vector    = (const float*)d_in[2];
    const float* w0 = (const float*)d_in[3];
    const float* b0 = (const float*)d_in[4];
    const float* w1 = (const float*)d_in[5];
    const float* b1 = (const float*)d_in[6];
    const float* w2 = (const float*)d_in[7];
    const float* b2 = (const float*)d_in[8];
    const float* w3 = (const float*)d_in[9];
    const float* b3 = (const float*)d_in[10];
    float* out = (float*)d_out;
    f16*   wf  = (f16*)d_ws;            // 576 KB of fragment buffers

    prep_w0 <<<dim3(64),  dim3(256), 0, stream>>>(w0, wf + WS_W0H, wf + WS_W0L);
    prep_whd<<<dim3(256), dim3(256), 0, stream>>>(w1, wf + WS_W1H, wf + WS_W1L);
    prep_whd<<<dim3(256), dim3(256), 0, stream>>>(w2, wf + WS_W2H, wf + WS_W2L);

    mlp_kernel<<<dim3(NPOSE * BPTS / TM), dim3(512), 0, stream>>>(
        x_world, inv_poses, b0, b1, b2, w3, b3, wf, out);
    select_kernel<<<dim3(BPTS / 256), dim3(256), 0, stream>>>(
        x_world, inv_poses, vector, out);
}